// Round 10
// baseline (47.618 us; speedup 1.0000x reference)
//
#include <hip/hip_runtime.h>

namespace {
constexpr int N_ELEMS  = 262144;
constexpr int N_NODES  = 263169;
constexpr int BLK      = 256;
constexpr int EPB      = 64;                  // elements per block (1 thread per (e,ip))
constexpr int NBLOCKS  = N_ELEMS / EPB;       // 4096

// folded material constants (fp32, match reference math)
constexpr float GC_2L0  = 0.09f;                 // G_C / (2*L_0)
constexpr float L0SQ    = 0.015f * 0.015f;
constexpr float MU_     = 80.76923076923077f;    // E/(2(1+nu))
constexpr float K_MOD   = 175.0f;                // lam + 2mu/3 (exact)
constexpr float PENALTY = 1799.82f;              // G_C/L_0*(1/PF_TOL^2-1)
}

typedef float vfloat4 __attribute__((ext_vector_type(4)));

__device__ __forceinline__ float waveReduce(float x) {
#pragma unroll
    for (int off = 32; off; off >>= 1) x += __shfl_down(x, off, 64);
    return x;
}

__global__ __launch_bounds__(256) void fused_energy(
    const float* __restrict__ u, const float* __restrict__ v,
    const float* __restrict__ c, const float* __restrict__ prev_c,
    const int* __restrict__ conn,
    const float* __restrict__ Nf, const float* __restrict__ dNdx,
    const float* __restrict__ B, const float* __restrict__ vol,
    float* __restrict__ partials)
{
    // Transposed tiles: col = element (or unit) in tile; every GLOBAL load in
    // this kernel is lane-linear (memcpy pattern); only 3 small gathers/thread.
    __shared__ vfloat4 ldsB[24 * 65];    // [f4row 0..23][elem 0..63] stride 65
    __shared__ vfloat4 ldsD[2 * 257];    // [f4row 0..1][unit 0..255] stride 257
    __shared__ float   ldsN[12 * 66];    // [c0..3,u0..3,v0..3][elem] stride 66

    const int k     = threadIdx.x;
    const int ebase = blockIdx.x * EPB;
    const long long t = (long long)blockIdx.x * BLK + k;   // nodal term id

    // ---- B staging: 1536 f4, pure unit-stride stream ---------------------
    const vfloat4* Bg = reinterpret_cast<const vfloat4*>(B) + (long long)ebase * 24;
#pragma unroll
    for (int r = 0; r < 6; ++r) {
        const int j = k + BLK * r;
        ldsB[(j % 24) * 65 + (j / 24)] = Bg[j];
    }

    // ---- dNdx staging: 512 f4, pure unit-stride stream -------------------
    const vfloat4* Dg = reinterpret_cast<const vfloat4*>(dNdx) + (long long)ebase * 8;
#pragma unroll
    for (int r = 0; r < 2; ++r) {
        const int j = k + BLK * r;
        ldsD[(j & 1) * 257 + (j >> 1)] = Dg[j];
    }

    // ---- nodal gather: conn is lane-linear; 3 gathers share one index ----
    const int m  = k >> 2;         // element within tile
    const int ip = k & 3;          // ip of this unit / node slot for gather
    const int idx = conn[4ll * ebase + k];
    ldsN[ip * 66 + m]       = c[idx];
    ldsN[(4 + ip) * 66 + m] = u[idx];
    ldsN[(8 + ip) * 66 + m] = v[idx];

    // ---- direct lane-linear loads (f4 index == global unit) --------------
    const vfloat4 Nr  = reinterpret_cast<const vfloat4*>(Nf)[4ll * ebase + k];
    const float   vip = vol[4ll * ebase + k];

    float Eirr = 0.f;
    if (t < N_NODES) {
        float d = fmaxf(prev_c[t] - c[t], 0.f);
        Eirr = 0.5f * PENALTY * d * d;
    }

    __syncthreads();

    // ---- read this unit's data from LDS ----------------------------------
    const float c0 = ldsN[0 * 66 + m], c1 = ldsN[1 * 66 + m];
    const float c2 = ldsN[2 * 66 + m], c3 = ldsN[3 * 66 + m];
    const float u0 = ldsN[4 * 66 + m], u1 = ldsN[5 * 66 + m];
    const float u2 = ldsN[6 * 66 + m], u3 = ldsN[7 * 66 + m];
    const float v0 = ldsN[8 * 66 + m], v1 = ldsN[9 * 66 + m];
    const float v2 = ldsN[10 * 66 + m], v3 = ldsN[11 * 66 + m];

    const vfloat4 dx = ldsD[k];           // [0][unit]
    const vfloat4 dy = ldsD[257 + k];     // [1][unit]

    const vfloat4 b0 = ldsB[(6 * ip + 0) * 65 + m];
    const vfloat4 b1 = ldsB[(6 * ip + 1) * 65 + m];
    const vfloat4 b2 = ldsB[(6 * ip + 2) * 65 + m];
    const vfloat4 b3 = ldsB[(6 * ip + 3) * 65 + m];
    const vfloat4 b4 = ldsB[(6 * ip + 4) * 65 + m];
    const vfloat4 b5 = ldsB[(6 * ip + 5) * 65 + m];

    // ---- compute one (e, ip) unit ----------------------------------------
    const float o0 = 1.f - c0, o1 = 1.f - c1, o2 = 1.f - c2, o3 = 1.f - c3;
    const float omc = Nr.x * o0 + Nr.y * o1 + Nr.z * o2 + Nr.w * o3;
    const float g   = omc * omc;
    const float cip = 1.f - omc;
    const float gx  = dx.x * c0 + dx.y * c1 + dx.z * c2 + dx.w * c3;
    const float gy  = dy.x * c0 + dy.y * c1 + dy.z * c2 + dy.w * c3;
    float Efr = GC_2L0 * (cip * cip + L0SQ * (gx * gx + gy * gy)) * vip;

    const float exx = b0.x * u0 + b0.y * v0 + b0.z * u1 + b0.w * v1
                    + b1.x * u2 + b1.y * v2 + b1.z * u3 + b1.w * v3;
    const float eyy = b2.x * u0 + b2.y * v0 + b2.z * u1 + b2.w * v1
                    + b3.x * u2 + b3.y * v2 + b3.z * u3 + b3.w * v3;
    const float gxy = b4.x * u0 + b4.y * v0 + b4.z * u1 + b4.w * v1
                    + b5.x * u2 + b5.y * v2 + b5.z * u3 + b5.w * v3;
    const float exy = 0.5f * gxy;
    const float tr  = exx + eyy, tr3 = tr * (1.f / 3.f);
    const float dxx = exx - tr3, dyy = eyy - tr3, dzz = -tr3;
    const float dev2 = dxx * dxx + dyy * dyy + dzz * dzz + 2.f * exy * exy;
    const float trp = fmaxf(tr, 0.f), trn = fminf(tr, 0.f);
    float Eel = ((0.5f * K_MOD * trp * trp + MU_ * dev2) * g
                 + 0.5f * K_MOD * trn * trn) * vip;

    // ---- block reduction -> contention-free partial store ----------------
    Eel  = waveReduce(Eel);
    Efr  = waveReduce(Efr);
    Eirr = waveReduce(Eirr);
    __shared__ float sE[4], sF[4], sI[4];
    const int lane = k & 63, wid = k >> 6;
    if (lane == 0) { sE[wid] = Eel; sF[wid] = Efr; sI[wid] = Eirr; }
    __syncthreads();
    if (k == 0) {
        float* p = partials + 3ll * blockIdx.x;
        p[0] = sE[0] + sE[1] + sE[2] + sE[3];
        p[1] = sF[0] + sF[1] + sF[2] + sF[3];
        p[2] = sI[0] + sI[1] + sI[2] + sI[3];
    }
}

__global__ __launch_bounds__(256) void final_reduce(
    const float* __restrict__ partials, float* __restrict__ out)
{
    float s0 = 0.f, s1 = 0.f, s2 = 0.f;
    for (int i = threadIdx.x; i < NBLOCKS; i += 256) {
        const float* p = partials + 3ll * i;
        s0 += p[0]; s1 += p[1]; s2 += p[2];
    }
    s0 = waveReduce(s0);
    s1 = waveReduce(s1);
    s2 = waveReduce(s2);
    __shared__ float sA[4], sB[4], sC[4];
    const int lane = threadIdx.x & 63, wid = threadIdx.x >> 6;
    if (lane == 0) { sA[wid] = s0; sB[wid] = s1; sC[wid] = s2; }
    __syncthreads();
    if (threadIdx.x == 0) {
        out[0] = sA[0] + sA[1] + sA[2] + sA[3];
        out[1] = sB[0] + sB[1] + sB[2] + sB[3];
        out[2] = sC[0] + sC[1] + sC[2] + sC[3];
    }
}

extern "C" void kernel_launch(void* const* d_in, const int* in_sizes, int n_in,
                              void* d_out, int out_size, void* d_ws, size_t ws_size,
                              hipStream_t stream) {
    const float* u      = (const float*)d_in[0];
    const float* v      = (const float*)d_in[1];
    const float* c      = (const float*)d_in[2];
    const float* prev_c = (const float*)d_in[3];
    const int*   conn   = (const int*)d_in[4];
    const float* Nf     = (const float*)d_in[5];
    const float* dNdx   = (const float*)d_in[6];
    const float* B      = (const float*)d_in[7];
    const float* vol    = (const float*)d_in[8];
    float* out      = (float*)d_out;
    float* partials = (float*)d_ws;   // 4096 * 3 floats = 48 KB

    fused_energy<<<NBLOCKS, BLK, 0, stream>>>(
        u, v, c, prev_c, conn, Nf, dNdx, B, vol, partials);
    final_reduce<<<1, BLK, 0, stream>>>(partials, out);
}